// Round 2
// baseline (1906.251 us; speedup 1.0000x reference)
//
#include <hip/hip_runtime.h>

// Problem constants (fixed by setup_inputs: B=16, DEPTH=15, X=H=128)
#define HB 128
#define B_ 16
#define TDEPTH 15
#define NN 32767                 // 2^15 - 1 nodes
#define NLEAF 16384              // level 14
#define LEAF_START 16383

__device__ __forceinline__ float sigm(float a) { return 1.0f / (1.0f + __expf(-a)); }
// tanh via exp, saturates cleanly at +-inf (no NaN)
__device__ __forceinline__ float tanh_f(float a) { return 1.0f - 2.0f / (__expf(2.0f * a) + 1.0f); }

// Leaf init: h = (1 - sigmoid(i[:128])) * tanh(i[128:]), i = x_row @ W_w + W_b.
// NPB leaves per 256-thread block. Thread t owns output column t (of 256).
// x values are block-uniform per (j,k) -> scalar loads; weights coalesced vector loads.
template <int NPB>
__global__ __launch_bounds__(256)
void leaf_kernel(const float* __restrict__ x, const float* __restrict__ Ww,
                 const float* __restrict__ Wb, float* __restrict__ out) {
    int bid = blockIdx.x;
    int b = bid >> 11;                    // NLEAF/NPB = 2048 groups per batch (NPB=8)
    int g = bid & 2047;
    long row0 = (long)b * NN + LEAF_START + (long)g * NPB;
    const float* xr = x + row0 * HB;      // NPB consecutive rows of 128
    int t = threadIdx.x;
    float bias = Wb[t];
    float acc[NPB];
#pragma unroll
    for (int j = 0; j < NPB; ++j) acc[j] = bias;
#pragma unroll 4
    for (int k = 0; k < HB; ++k) {
        float w = Ww[k * (2 * HB) + t];   // coalesced, L2-resident
#pragma unroll
        for (int j = 0; j < NPB; ++j) acc[j] += xr[j * HB + k] * w;  // uniform -> s_load
    }
    __shared__ float sv[NPB][2 * HB];
#pragma unroll
    for (int j = 0; j < NPB; ++j) sv[j][t] = acc[j];
    __syncthreads();
    if (t < HB) {
#pragma unroll
        for (int j = 0; j < NPB; ++j) {
            float f0 = sigm(sv[j][t]);
            float c0 = tanh_f(sv[j][t + HB]);
            out[(row0 + j) * HB + t] = (1.0f - f0) * c0;
        }
    }
}

// Internal level: NPB nodes per 256-thread block.
// GEMM1 (f = sigmoid(hc @ Uf_w + b)): thread t owns column t; children h values
// (block-uniform addresses) via scalar loads; weights coalesced.
// GEMM2 (cand = tanh((f*hc) @ Uh_w + b)): g staged in LDS, read as wave-uniform
// broadcasts; thread t owns column t&127 for NPB/2 nodes (picked by t>>7).
template <int NPB>
__global__ __launch_bounds__(256)
void level_kernel(const float* __restrict__ Ufw, const float* __restrict__ Ufb,
                  const float* __restrict__ Uhw, const float* __restrict__ Uhb,
                  const float* __restrict__ hin, float* __restrict__ hout,
                  int start, int gshift) {
    int bid = blockIdx.x;
    int b = bid >> gshift;
    int g = bid & ((1 << gshift) - 1);
    int i0 = g * NPB;
    long base = (long)b * NN;
    // children of nodes i0..i0+NPB-1: rows 2*start+1+2*i0 .. +2*NPB-1 (contiguous)
    const float* hc = hin + (base + 2 * start + 1 + 2 * i0) * HB;  // NPB*256 floats
    int t = threadIdx.x;

    float bias = Ufb[t];
    float acc[NPB];
#pragma unroll
    for (int j = 0; j < NPB; ++j) acc[j] = bias;
#pragma unroll 4
    for (int k = 0; k < 2 * HB; ++k) {
        float w = Ufw[k * (2 * HB) + t];  // coalesced, L2-resident
#pragma unroll
        for (int j = 0; j < NPB; ++j) acc[j] += hc[j * (2 * HB) + k] * w;  // s_load
    }

    __shared__ float glds[NPB][2 * HB];
    __shared__ float flds[NPB][2 * HB];
#pragma unroll
    for (int j = 0; j < NPB; ++j) {
        float f = sigm(acc[j]);
        flds[j][t] = f;
        glds[j][t] = f * hc[j * (2 * HB) + t];  // coalesced vector reload (L1/L2 hit)
    }
    __syncthreads();

    constexpr int JH = (NPB >= 2) ? NPB / 2 : 1;
    int c = t & (HB - 1);
    int j0 = (NPB >= 2) ? (t >> 7) * (NPB / 2) : 0;
    float b2 = Uhb[c];
    float acc2[JH];
#pragma unroll
    for (int jj = 0; jj < JH; ++jj) acc2[jj] = b2;
#pragma unroll 4
    for (int k = 0; k < 2 * HB; ++k) {
        float w2 = Uhw[k * HB + c];       // coalesced (both halves hit same lines)
#pragma unroll
        for (int jj = 0; jj < JH; ++jj) acc2[jj] += glds[j0 + jj][k] * w2;  // broadcast
    }
    if (NPB >= 2 || t < HB) {
#pragma unroll
        for (int jj = 0; jj < JH; ++jj) {
            int j = j0 + jj;
            float cand = tanh_f(acc2[jj]);
            float f1 = flds[j][c], f2 = flds[j][c + HB];
            float h1 = hc[j * (2 * HB) + c], h2 = hc[j * (2 * HB) + c + HB];
            float hn = (1.0f - f1 - f2) * cand + f1 * h1 + f2 * h2;
            hout[(base + start + i0 + j) * HB + c] = hn;
        }
    }
}

extern "C" void kernel_launch(void* const* d_in, const int* in_sizes, int n_in,
                              void* d_out, int out_size, void* d_ws, size_t ws_size,
                              hipStream_t stream) {
    const float* x   = (const float*)d_in[0];
    const float* Ww  = (const float*)d_in[1];
    const float* Wb  = (const float*)d_in[2];
    const float* Ufw = (const float*)d_in[3];
    const float* Ufb = (const float*)d_in[4];
    const float* Uhw = (const float*)d_in[5];
    const float* Uhb = (const float*)d_in[6];
    float* out = (float*)d_out;

    // Leaves: 16*16384/8 = 32768 blocks. Internal init-h is dead (overwritten) -- skipped.
    leaf_kernel<8><<<B_ * NLEAF / 8, 256, 0, stream>>>(x, Ww, Wb, out);

    // Levels 13..0, NPB = min(2^l, 8) nodes/block. hin==hout: regions disjoint.
    for (int l = TDEPTH - 2; l >= 0; --l) {
        int start = (1 << l) - 1;
        int npb_lg = (l < 3) ? l : 3;
        int gshift = l - npb_lg;
        int grid = B_ << gshift;
        switch (npb_lg) {
            case 3: level_kernel<8><<<grid, 256, 0, stream>>>(Ufw, Ufb, Uhw, Uhb, out, out, start, gshift); break;
            case 2: level_kernel<4><<<grid, 256, 0, stream>>>(Ufw, Ufb, Uhw, Uhb, out, out, start, gshift); break;
            case 1: level_kernel<2><<<grid, 256, 0, stream>>>(Ufw, Ufb, Uhw, Uhb, out, out, start, gshift); break;
            case 0: level_kernel<1><<<grid, 256, 0, stream>>>(Ufw, Ufb, Uhw, Uhb, out, out, start, gshift); break;
        }
    }
}